// Round 15
// baseline (190.887 us; speedup 1.0000x reference)
//
#include <hip/hip_runtime.h>
#include <math.h>

#define BB 64
#define SS 21
#define NSAMP 3000
#define HID 500
#define SECN 6
#define NN 2
#define OUTD 128
#define NPROTO 25
#define NCLS 5
#define NHEAD 4
#define BS (BB*SS)          // 1344
#define NSAMPLE (BS*NN)     // 2688

#define C500 (-0.0184206807439523674f)   // -ln(1e4)/500
#define C128 (-0.07195578415606439f)     // -ln(1e4)/128
#define LSCALE 0.00745355992499929898f   // 1/(6*sqrt(500))

// ws float offsets
#define WS_W2HI 5376
#define WS_W2LO 8448
#define WS_W3HI 11520
#define WS_W3LO 23808
#define WS_P3   36096
#define WS_C3   55296
#define WS_WQT  55424
#define WS_V    727424
#define WS_CTX  (WS_V + 520192)

typedef __attribute__((ext_vector_type(8))) short short8;
typedef __attribute__((ext_vector_type(4))) short short4v;
typedef __attribute__((ext_vector_type(4))) float floatx4;

__device__ __forceinline__ short f2bf(float f) {
  unsigned u = __float_as_uint(f);
  u += 0x7FFF + ((u >> 16) & 1);          // RNE to bf16
  return (short)(u >> 16);
}
__device__ __forceinline__ float bf2f(short h) {
  return __uint_as_float(((unsigned)(unsigned short)h) << 16);
}

// ---------------- Kernel 0: weight splits (MFMA-fragment order) + VQ prep + wq transpose ----------------
__global__ __launch_bounds__(256) void prep_all_kernel(
    const float* __restrict__ w2, const float* __restrict__ w3,
    short* __restrict__ w2hi, short* __restrict__ w2lo,
    short* __restrict__ w3hi, short* __restrict__ w3lo,
    const float* __restrict__ protos, const float* __restrict__ fc2w,
    const float* __restrict__ fcw, const float* __restrict__ fcb,
    const float* __restrict__ fc2b,
    float* __restrict__ P3, float* __restrict__ c3,
    const float* __restrict__ wq, float* __restrict__ wqT) {
  __shared__ __align__(16) float p2row[256];
  __shared__ float red[256];
  __shared__ float tile[64][65];
  const int t = threadIdx.x;
  if (blockIdx.x < 120) {
    int idx = blockIdx.x * 256 + t;
    if (idx < 6144) {
      int ic = idx & 31, ck = idx >> 5, k = ck % 3, c = ck / 3;
      float v = w2[c * 96 + ic * 3 + k];
      int dst = (((k * 4 + (c >> 4)) * 64) + ((ic >> 3) * 16 + (c & 15))) * 8 + (ic & 7);
      short hi = f2bf(v);
      short lo = f2bf(v - bf2f(hi));
      w2hi[dst] = hi; w2lo[dst] = lo;
    } else if (idx < 30720) {
      int j = idx - 6144;
      int ic = j & 63, ck = j >> 6, k = ck % 3, c = ck / 3;
      float v = w3[(c * 64 + ic) * 3 + k];
      int s = k * 2 + (ic >> 5);
      int dst = (((s * 8 + (c >> 4)) * 64) + (((ic & 31) >> 3) * 16 + (c & 15))) * 8 + (ic & 7);
      short hi = f2bf(v);
      short lo = f2bf(v - bf2f(hi));
      w3hi[dst] = hi; w3lo[dst] = lo;
    }
    return;
  }
  if (blockIdx.x >= 145) {               // wq transpose: 32 tile-blocks
    int tid = blockIdx.x - 145;
    int h0 = (tid >> 2) * 64, c0 = (tid & 3) * 64;
    for (int e = t; e < 4096; e += 256) {
      int i = e >> 6, j = e & 63;
      if (h0 + i < 500) tile[j][i] = wq[(h0 + i) * 256 + c0 + j];
    }
    __syncthreads();
    for (int e = t; e < 4096; e += 256) {
      int c = e >> 6, hh = e & 63;
      if (h0 + hh < 500) wqT[(c0 + c) * 500 + h0 + hh] = tile[c][hh];
    }
    return;
  }
  const int p = blockIdx.x - 120, j = t;
  {
    const float4* pr = reinterpret_cast<const float4*>(protos + p * 128);
    const float4* wr = reinterpret_cast<const float4*>(fc2w + j * 128);
    float4 a4 = make_float4(0.f, 0.f, 0.f, 0.f);
    for (int c4 = 0; c4 < 32; c4++) {
      float4 a = pr[c4], b = wr[c4];
      a4.x += a.x * b.x; a4.y += a.y * b.y; a4.z += a.z * b.z; a4.w += a.w * b.w;
    }
    float v = (a4.x + a4.y) + (a4.z + a4.w);
    p2row[j] = v;
    float contrib = v * fcb[j];
    if (j < 128) {
      float pv = protos[p * 128 + j];
      contrib += pv * fc2b[j] - 0.5f * pv * pv;
    }
    red[j] = contrib;
  }
  __syncthreads();
  for (int s = 128; s > 0; s >>= 1) {
    if (j < s) red[j] += red[j + s];
    __syncthreads();
  }
  if (j == 0) c3[p] = red[0];
  for (int k = j; k < 768; k += 256) {
    const float4* fr = reinterpret_cast<const float4*>(fcw + k * 256);
    const float4* p2 = reinterpret_cast<const float4*>(p2row);
    float4 a4 = make_float4(0.f, 0.f, 0.f, 0.f);
    for (int j4 = 0; j4 < 64; j4++) {
      float4 a = p2[j4], b = fr[j4];
      a4.x += a.x * b.x; a4.y += a.y * b.y; a4.z += a.z * b.z; a4.w += a.w * b.w;
    }
    P3[p * 768 + k] = (a4.x + a4.y) + (a4.z + a4.w);
  }
}

// ---------------- Kernel 1b: fused xsum -> ks -> v (4 samples/block, 336 blocks, K-split) ----------------
#define MBX 4
__global__ __launch_bounds__(512) void attn_b_kernel(
    const float* __restrict__ x, const float* __restrict__ wk,
    const float* __restrict__ wqT, float* __restrict__ v) {
  __shared__ __align__(16) float pesum[500];
  __shared__ __align__(16) float xs[MBX * 500];
  __shared__ __align__(16) float ksp[2 * 256 * MBX];
  __shared__ __align__(16) float ks_t[256 * MBX];
  const int blk = blockIdx.x, t = threadIdx.x;

  if (t < 125) {
    float div0 = expf((float)(4 * t) * C500);
    float div1 = expf((float)(4 * t + 2) * C500);
    float s0 = 0.f, c0 = 0.f, s1 = 0.f, c1 = 0.f;
#pragma unroll
    for (int s = 0; s < SECN; s++) {
      float a0 = (float)s * div0, a1 = (float)s * div1;
      s0 += sinf(a0); c0 += cosf(a0);
      s1 += sinf(a1); c1 += cosf(a1);
    }
    reinterpret_cast<float4*>(pesum)[t] = make_float4(s0, c0, s1, c1);
  }
  __syncthreads();

  for (int e = t; e < MBX * 125; e += 512) {
    int m = e / 125, h4 = e % 125;
    const float4* xr = reinterpret_cast<const float4*>(x) + (blk * MBX + m) * 750;
    float4 a = xr[h4];
#pragma unroll
    for (int s = 1; s < SECN; s++) {
      float4 b = xr[s * 125 + h4];
      a.x += b.x; a.y += b.y; a.z += b.z; a.w += b.w;
    }
    float4 pe = reinterpret_cast<float4*>(pesum)[h4];
    a.x += pe.x; a.y += pe.y; a.z += pe.z; a.w += pe.w;
    reinterpret_cast<float4*>(xs)[m * 125 + h4] = a;
  }
  __syncthreads();

  {
    int c = t & 255, kh = t >> 8;
    float acc[MBX];
#pragma unroll
    for (int m = 0; m < MBX; m++) acc[m] = 0.f;
    int b4 = kh ? 63 : 0, e4 = kh ? 125 : 63;
    const float4* xsb = reinterpret_cast<const float4*>(xs);
    for (int i4 = b4; i4 < e4; i4++) {
      int i = i4 * 4;
      float w0 = wk[(i + 0) * 256 + c];
      float w1 = wk[(i + 1) * 256 + c];
      float w2v = wk[(i + 2) * 256 + c];
      float w3v = wk[(i + 3) * 256 + c];
#pragma unroll
      for (int m = 0; m < MBX; m++) {
        float4 xv = xsb[m * 125 + i4];
        acc[m] += xv.x * w0 + xv.y * w1 + xv.z * w2v + xv.w * w3v;
      }
    }
#pragma unroll
    for (int m = 0; m < MBX; m++)
      ksp[(kh * 256 + c) * MBX + m] = acc[m];
  }
  __syncthreads();
  for (int e = t; e < 256 * MBX; e += 512) ks_t[e] = ksp[e] + ksp[256 * MBX + e];
  __syncthreads();

  if (t < 500) {
    int h = t;
#pragma unroll
    for (int n = 0; n < 2; n++) {
      float acc[MBX];
#pragma unroll
      for (int m = 0; m < MBX; m++) acc[m] = 0.f;
      const float* wcol = wqT + (n * 128) * 500 + h;
      const floatx4* ktb = (const floatx4*)ks_t + n * 128;
      for (int c = 0; c < 128; c++) {
        float w = wcol[c * 500];
        floatx4 k0 = ktb[c];
        acc[0] += w * k0[0]; acc[1] += w * k0[1]; acc[2] += w * k0[2]; acc[3] += w * k0[3];
      }
#pragma unroll
      for (int m = 0; m < MBX; m++)
        v[((blk * MBX + m) * 2 + n) * 500 + h] = acc[m];
    }
  }
}

// ---------------- Kernel 1c: logits = (x+pe).v + gumbel -> argmax ----------------
__global__ __launch_bounds__(192) void attn_c_kernel(
    const float* __restrict__ x, const float* __restrict__ v,
    const float* __restrict__ gumbel, int* __restrict__ sec_idx) {
  __shared__ float lgsh[NN][SECN];
  const int bs = blockIdx.x, t = threadIdx.x;
  const int s = t >> 5, lane = t & 31;
  const float4* x4 = reinterpret_cast<const float4*>(x) + bs * 750 + s * 125;
  const float4* v0 = reinterpret_cast<const float4*>(v) + bs * 250;
  const float4* v1 = v0 + 125;
  float a0 = 0.f, a1 = 0.f;
  for (int h4 = lane; h4 < 125; h4 += 32) {
    float4 xv = x4[h4];
    float div0 = expf((float)(4 * h4) * C500);
    float div1 = expf((float)(4 * h4 + 2) * C500);
    float ang0 = (float)s * div0, ang1 = (float)s * div1;
    xv.x += sinf(ang0); xv.y += cosf(ang0);
    xv.z += sinf(ang1); xv.w += cosf(ang1);
    float4 w0 = v0[h4], w1 = v1[h4];
    a0 += xv.x * w0.x + xv.y * w0.y + xv.z * w0.z + xv.w * w0.w;
    a1 += xv.x * w1.x + xv.y * w1.y + xv.z * w1.z + xv.w * w1.w;
  }
#pragma unroll
  for (int m = 16; m >= 1; m >>= 1) {
    a0 += __shfl_xor(a0, m);
    a1 += __shfl_xor(a1, m);
  }
  if (lane == 0) {
    lgsh[0][s] = a0 * LSCALE + gumbel[(bs * 2 + 0) * SECN + s];
    lgsh[1][s] = a1 * LSCALE + gumbel[(bs * 2 + 1) * SECN + s];
  }
  __syncthreads();
  if (t < 2) {
    int best = 0; float bv = lgsh[t][0];
    for (int i = 1; i < SECN; i++) {
      float q = lgsh[t][i];
      if (q > bv) { bv = q; best = i; }
    }
    sec_idx[bs * 2 + t] = best;
  }
}

// ---------------- Kernel 2: conv encoder (MFMA; conv1 reads x from global) + VQ ----------------
// LDS map (bytes):
//  [0,20800)      act1_hi[130][40] / act1_lo          | featsh[768]@0 + sc25@3072 (after 3b)
//  [20800,30048)  act2p_hi[34][68] / act2p_lo
//  [30048,46944)  act2t[64][64] swizzled | act3t[32][132] ; bnd[64]@46432
#define CONV_LDS 46944
#define ST2P 68
__global__ __launch_bounds__(512, 6) void conv_kernel(
    const float* __restrict__ x, const int* __restrict__ sec_idx,
    const float* __restrict__ w1, const float* __restrict__ b1,
    const float* __restrict__ bn1g, const float* __restrict__ bn1b,
    const short* __restrict__ w2hi, const short* __restrict__ w2lo,
    const float* __restrict__ b2,
    const float* __restrict__ bn2g, const float* __restrict__ bn2b,
    const short* __restrict__ w3hi, const short* __restrict__ w3lo,
    const float* __restrict__ b3,
    const float* __restrict__ bn3g, const float* __restrict__ bn3b,
    const float* __restrict__ P3, const float* __restrict__ c3,
    int* __restrict__ proto_idx) {
  __shared__ __align__(16) char smem[CONV_LDS];
  short* act1_hi  = (short*)smem;               // [130][40]
  short* act1_lo  = (short*)(smem + 10400);
  short* act2p_hi = (short*)(smem + 20800);     // [34][68]
  short* act2p_lo = (short*)(smem + 25424);
  float* featsh   = (float*)smem;               // [768] (alias act1, after 3b)
  float* sc25     = (float*)(smem + 3072);      // [25]
  float* act2t = (float*)(smem + 30048);        // [64][64] swizzled (half)
  float* act3t = (float*)(smem + 30048);        // [32][132]
  float* bnd   = (float*)(smem + 46432);        // [64] boundary partial

  const int sample = blockIdx.x;
  const int t = threadIdx.x;
  const int bsIdx = sample >> 1;
  const float bnscale = rsqrtf(1.0f + 1e-5f);
  const int wv = t >> 6, l = t & 63, lr = l & 15, lg2 = l >> 4;

  // ---- phase 1: zero act1 + act2p pad rows (no x staging — conv1 reads global) ----
  {
    if (t < 200) {
      int r = t / 40; r = (r == 0) ? 0 : 125 + r;
      int idx = r * 40 + t % 40;
      act1_hi[idx] = 0; act1_lo[idx] = 0;
    }
    if (t >= 256 && t < 256 + 153) {
      int tt = t - 256;
      for (int i = tt; i < 612; i += 153) {     // act2p rows 0, 26..33
        int r = i / ST2P; r = (r == 0) ? 0 : 25 + r;
        int idx = r * ST2P + i % ST2P;
        act2p_hi[idx] = 0; act2p_lo[idx] = 0;
      }
    }
  }
  // no barrier needed: phase 2 writes only act1 main rows; pads synced by the
  // barrier after phase 2 (before any pad consumer).

  // ---- phase 2: conv1 + relu + pool4 + bn -> act1 (x direct from global, f4 reads) ----
  {
    int sec = sec_idx[sample];
    const float* src = &x[bsIdx * NSAMP + sec * HID];   // 16B-aligned
    int ic = t & 31;
    float w0 = w1[ic * 3], w1v = w1[ic * 3 + 1], w2v = w1[ic * 3 + 2];
    float bb = b1[ic];
    float g = bn1g[ic] * bnscale, be = bn1b[ic];
    for (int p = t >> 5; p < 125; p += 16) {
      int base = 4 * p;
      float xm1, x0, x1, x2, x3, x4;
      float4 cur = *reinterpret_cast<const float4*>(src + base);
      x0 = cur.x; x1 = cur.y; x2 = cur.z; x3 = cur.w;
      if (p == 0) {
        xm1 = 0.f;
      } else {
        float4 prev = *reinterpret_cast<const float4*>(src + base - 4);
        xm1 = prev.w;
      }
      x4 = (base + 4 < HID) ? src[base + 4] : 0.f;
      float a0 = bb + w0 * xm1 + w1v * x0 + w2v * x1;
      float a1 = bb + w0 * x0  + w1v * x1 + w2v * x2;
      float a2 = bb + w0 * x1  + w1v * x2 + w2v * x3;
      float a3 = bb + w0 * x2  + w1v * x3 + w2v * x4;
      float m = fmaxf(fmaxf(fmaxf(fmaxf(a0, a1), a2), a3), 0.f);
      float v = m * g + be;
      short hi = f2bf(v);
      short lo = f2bf(v - bf2f(hi));
      act1_hi[(p + 1) * 40 + ic] = hi;
      act1_lo[(p + 1) * 40 + ic] = lo;
    }
  }
  __syncthreads();

#define A2T(r, c) act2t[(r) * 64 + ((((c) >> 2) ^ ((r) & 15)) << 2) + ((c) & 3)]
  // ---- phases 3a/4a, 3b/4b: conv2 MFMA + pool5 over two position halves ----
#pragma unroll
  for (int h = 0; h < 2; h++) {
    {
      int tl = wv & 3, mh = wv >> 2;
      int lrow = tl * 16 + lr;
      floatx4 acc[2];
      acc[0] = (floatx4){0.f, 0.f, 0.f, 0.f};
      acc[1] = acc[0];
#pragma unroll
      for (int s = 0; s < 3; s++) {
        short8 Ah[2], Al[2], Bh, Bl;
#pragma unroll
        for (int j = 0; j < 2; j++) {
          int m = mh * 2 + j;
          int aoff = ((s * 4 + m) * 64 + l) * 8;
          Ah[j] = *(const short8*)(w2hi + aoff);
          Al[j] = *(const short8*)(w2lo + aoff);
        }
        {
          int boff = (h * 64 + lrow + s) * 40 + lg2 * 8;
          Bh = *(const short8*)(act1_hi + boff);
          Bl = *(const short8*)(act1_lo + boff);
        }
#pragma unroll
        for (int j = 0; j < 2; j++) {
          acc[j] = __builtin_amdgcn_mfma_f32_16x16x32_bf16(Ah[j], Bh, acc[j], 0, 0, 0);
          acc[j] = __builtin_amdgcn_mfma_f32_16x16x32_bf16(Ah[j], Bl, acc[j], 0, 0, 0);
          acc[j] = __builtin_amdgcn_mfma_f32_16x16x32_bf16(Al[j], Bh, acc[j], 0, 0, 0);
        }
      }
#pragma unroll
      for (int j = 0; j < 2; j++) {
        int m = mh * 2 + j;
        int swz = (m * 4 + lg2) ^ lr;
        *(floatx4*)(act2t + lrow * 64 + swz * 4) = acc[j];
      }
    }
    __syncthreads();
    {
      int ic = t & 63;
      float bb = b2[ic], g = bn2g[ic] * bnscale, be = bn2b[ic];
      if (h == 0) {
        for (int pw = t >> 6; pw < 13; pw += 8) {
          if (pw < 12) {
            int base = 5 * pw;
            float m = A2T(base, ic);
            m = fmaxf(m, A2T(base + 1, ic));
            m = fmaxf(m, A2T(base + 2, ic));
            m = fmaxf(m, A2T(base + 3, ic));
            m = fmaxf(m, A2T(base + 4, ic));
            float v = fmaxf(m + bb, 0.f) * g + be;
            short hi = f2bf(v);
            short lo = f2bf(v - bf2f(hi));
            act2p_hi[(pw + 1) * ST2P + ic] = hi;
            act2p_lo[(pw + 1) * ST2P + ic] = lo;
          } else {
            float m = A2T(60, ic);
            m = fmaxf(m, A2T(61, ic));
            m = fmaxf(m, A2T(62, ic));
            m = fmaxf(m, A2T(63, ic));
            bnd[ic] = m;
          }
        }
      } else {
        for (int pw = 12 + (t >> 6); pw < 25; pw += 8) {
          float m;
          if (pw == 12) {
            m = fmaxf(bnd[ic], A2T(0, ic));
          } else {
            int base = 5 * pw - 64;
            m = A2T(base, ic);
            m = fmaxf(m, A2T(base + 1, ic));
            m = fmaxf(m, A2T(base + 2, ic));
            m = fmaxf(m, A2T(base + 3, ic));
            m = fmaxf(m, A2T(base + 4, ic));
          }
          float v = fmaxf(m + bb, 0.f) * g + be;
          short hi = f2bf(v);
          short lo = f2bf(v - bf2f(hi));
          act2p_hi[(pw + 1) * ST2P + ic] = hi;
          act2p_lo[(pw + 1) * ST2P + ic] = lo;
        }
      }
    }
    __syncthreads();
  }
#undef A2T

  // ---- phase 5: conv3 MFMA — wave wv owns ch-group wv; B via 2x b64 ----
  {
    floatx4 acc[2];
#pragma unroll
    for (int nn = 0; nn < 2; nn++) acc[nn] = (floatx4){0.f, 0.f, 0.f, 0.f};
#pragma unroll
    for (int s = 0; s < 6; s++) {
      short8 Ah, Al, Bh[2], Bl[2];
      {
        int aoff = ((s * 8 + wv) * 64 + l) * 8;
        Ah = *(const short8*)(w3hi + aoff);
        Al = *(const short8*)(w3lo + aoff);
      }
#pragma unroll
      for (int nn = 0; nn < 2; nn++) {
        int boff = (nn * 16 + lr + (s >> 1)) * ST2P + (s & 1) * 32 + lg2 * 8;
        short4v h0 = *(const short4v*)(act2p_hi + boff);
        short4v h1 = *(const short4v*)(act2p_hi + boff + 4);
        short4v l0 = *(const short4v*)(act2p_lo + boff);
        short4v l1 = *(const short4v*)(act2p_lo + boff + 4);
        Bh[nn] = (short8){h0[0], h0[1], h0[2], h0[3], h1[0], h1[1], h1[2], h1[3]};
        Bl[nn] = (short8){l0[0], l0[1], l0[2], l0[3], l1[0], l1[1], l1[2], l1[3]};
      }
#pragma unroll
      for (int nn = 0; nn < 2; nn++) {
        acc[nn] = __builtin_amdgcn_mfma_f32_16x16x32_bf16(Ah, Bh[nn], acc[nn], 0, 0, 0);
        acc[nn] = __builtin_amdgcn_mfma_f32_16x16x32_bf16(Ah, Bl[nn], acc[nn], 0, 0, 0);
        acc[nn] = __builtin_amdgcn_mfma_f32_16x16x32_bf16(Al, Bh[nn], acc[nn], 0, 0, 0);
      }
    }
#pragma unroll
    for (int nn = 0; nn < 2; nn++) {
      int p = nn * 16 + lr;
      *(floatx4*)(act3t + p * 132 + wv * 16 + lg2 * 4) = acc[nn];
    }
  }
  __syncthreads();

  // ---- phase 6: pool4 + bias + relu + bn -> featsh ----
  {
    int c = t & 127;
    float bb = b3[c], g = bn3g[c] * bnscale, be = bn3b[c];
    for (int pw = t >> 7; pw < 6; pw += 4) {
      int base = 4 * pw;
      float m = act3t[base * 132 + c];
      m = fmaxf(m, act3t[(base + 1) * 132 + c]);
      m = fmaxf(m, act3t[(base + 2) * 132 + c]);
      m = fmaxf(m, act3t[(base + 3) * 132 + c]);
      float v = fmaxf(m + bb, 0.f) * g + be;
      featsh[c * 6 + pw] = v;
    }
  }
  __syncthreads();

  // ---- phase 7: folded VQ scores + argmax ----
  if (t < NPROTO * 8) {
    int p = t >> 3, part = t & 7;
    const float4* pr = reinterpret_cast<const float4*>(P3 + p * 768 + part * 96);
    const float4* fr = reinterpret_cast<const float4*>(featsh + part * 96);
    float4 a4 = make_float4(0.f, 0.f, 0.f, 0.f);
#pragma unroll
    for (int i = 0; i < 24; i++) {
      float4 w = pr[i], f = fr[i];
      a4.x += w.x * f.x; a4.y += w.y * f.y; a4.z += w.z * f.z; a4.w += w.w * f.w;
    }
    float a = (a4.x + a4.y) + (a4.z + a4.w);
    a += __shfl_xor(a, 1);
    a += __shfl_xor(a, 2);
    a += __shfl_xor(a, 4);
    if (part == 0) sc25[p] = a + c3[p];
  }
  __syncthreads();
  if (t == 0) {
    int best = 0; float bv = sc25[0];
    for (int i = 1; i < NPROTO; i++) {
      float v = sc25[i];
      if (v > bv) { bv = v; best = i; }
    }
    proto_idx[sample] = best;
  }
}

// ---------------- Kernel 3ab: fused qkv + attention per (b, head) ----------------
__global__ __launch_bounds__(256) void seq_qk_attn_kernel(
    const int* __restrict__ proto_idx, const float* __restrict__ protos,
    const float* __restrict__ inw, const float* __restrict__ inb,
    float* __restrict__ ctxbuf) {
  __shared__ __align__(16) float hsh[SS * OUTD];
  __shared__ float qs_[SS][32], ks_[SS][32], vs_[SS][32];
  __shared__ float sc_[SS][SS + 1];
  const int b = blockIdx.x >> 2, hd = blockIdx.x & 3;
  const int t = threadIdx.x;

  for (int o = t; o < SS * OUTD; o += 256) {
    int s = o >> 7, d = o & 127;
    int i0 = proto_idx[(b * SS + s) * 2];
    int i1 = proto_idx[(b * SS + s) * 2 + 1];
    float pc = 0.5f * (protos[i0 * OUTD + d] + protos[i1 * OUTD + d]);
    float div = expf((float)(2 * (d >> 1)) * C128);
    float ang = (float)s * div;
    float pe = (d & 1) ? cosf(ang) : sinf(ang);
    hsh[o] = pc + pe;
  }
  __syncthreads();

  for (int o = t; o < SS * 96; o += 256) {
    int s = o / 96, j = o % 96;
    int sec = j >> 5, dd = j & 31;
    int col = sec * 128 + hd * 32 + dd;
    float a = inb[col];
    const float4* hr = reinterpret_cast<const float4*>(&hsh[s * OUTD]);
    for (int d4 = 0; d4 < 32; d4++) {
      float4 h4 = hr[d4];
      int d = d4 * 4;
      a += h4.x * inw[(d + 0) * 384 + col] + h4.y * inw[(d + 1) * 384 + col]
         + h4.z * inw[(d + 2) * 384 + col] + h4.w * inw[(d + 3) * 384 + col];
    }
    if (sec == 0) qs_[s][dd] = a;
    else if (sec == 1) ks_[s][dd] = a;
    else vs_[s][dd] = a;
  }
  __syncthreads();

  for (int e = t; e < SS * SS; e += 256) {
    int qs = e / SS, ks = e % SS;
    float a = 0.f;
#pragma unroll
    for (int d = 0; d < 32; d++) a += qs_[qs][d] * ks_[ks][d];
    sc_[qs][ks] = a * 0.17677669529663689f;
  }
  __syncthreads();
  if (t < SS) {
    float mx = sc_[t][0];
    for (int i = 1; i < SS; i++) mx = fmaxf(mx, sc_[t][i]);
    float sum = 0.f;
    for (int i = 0; i < SS; i++) { float e = expf(sc_[t][i] - mx); sc_[t][i] = e; sum += e; }
    float inv = 1.f / sum;
    for (int i = 0; i < SS; i++) sc_[t][i] *= inv;
  }
  __syncthreads();
  for (int e = t; e < SS * 32; e += 256) {
    int qs = e >> 5, dd = e & 31;
    float a = 0.f;
#pragma unroll
    for (int ks = 0; ks < SS; ks++) a += sc_[qs][ks] * vs_[ks][dd];
    ctxbuf[(b * SS + qs) * OUTD + hd * 32 + dd] = a;
  }
}

// ---------------- Kernel 3c: out proj + LN1 + FF + LN2 + classifier ----------------
__global__ __launch_bounds__(128) void seq_tail_kernel(
    const int* __restrict__ proto_idx, const float* __restrict__ protos,
    const float* __restrict__ ctxbuf,
    const float* __restrict__ outw, const float* __restrict__ outb,
    const float* __restrict__ ln1g, const float* __restrict__ ln1b,
    const float* __restrict__ ff1w, const float* __restrict__ ff1b,
    const float* __restrict__ ff2w, const float* __restrict__ ff2b,
    const float* __restrict__ ln2g, const float* __restrict__ ln2b,
    const float* __restrict__ clfw, const float* __restrict__ clfb,
    float* __restrict__ out) {
  __shared__ __align__(16) float rowA[OUTD];
  __shared__ __align__(16) float rowB[OUTD];
  __shared__ float lds2[2];
  const int bs = blockIdx.x, t = threadIdx.x;
  const int s = bs % SS;

  rowA[t] = ctxbuf[bs * OUTD + t];
  __syncthreads();
  float a = outb[t];
  {
    const float4* cr = reinterpret_cast<const float4*>(rowA);
    for (int e4 = 0; e4 < 32; e4++) {
      float4 c4 = cr[e4];
      int e = e4 * 4;
      a += c4.x * outw[(e + 0) * OUTD + t] + c4.y * outw[(e + 1) * OUTD + t]
         + c4.z * outw[(e + 2) * OUTD + t] + c4.w * outw[(e + 3) * OUTD + t];
    }
  }
  float hv;
  {
    int i0 = proto_idx[bs * 2], i1 = proto_idx[bs * 2 + 1];
    float pc = 0.5f * (protos[i0 * OUTD + t] + protos[i1 * OUTD + t]);
    float div = expf((float)(2 * (t >> 1)) * C128);
    float ang = (float)s * div;
    float pe = (t & 1) ? cosf(ang) : sinf(ang);
    hv = pc + pe;
  }
  float tmp = hv + a;
  {
    float v = tmp;
#pragma unroll
    for (int k = 32; k >= 1; k >>= 1) v += __shfl_xor(v, k);
    if ((t & 63) == 0) lds2[t >> 6] = v;
    __syncthreads();
    float m = (lds2[0] + lds2[1]) * (1.0f / OUTD);
    __syncthreads();
    float u = tmp - m;
    float w = u * u;
#pragma unroll
    for (int k = 32; k >= 1; k >>= 1) w += __shfl_xor(w, k);
    if ((t & 63) == 0) lds2[t >> 6] = w;
    __syncthreads();
    float var = (lds2[0] + lds2[1]) * (1.0f / OUTD);
    __syncthreads();
    rowA[t] = u * rsqrtf(var + 1e-5f) * ln1g[t] + ln1b[t];
  }
  __syncthreads();
  {
    float r = ff1b[t];
    const float4* hr = reinterpret_cast<const float4*>(rowA);
    for (int e4 = 0; e4 < 32; e4++) {
      float4 h4 = hr[e4];
      int e = e4 * 4;
      r += h4.x * ff1w[(e + 0) * OUTD + t] + h4.y * ff1w[(e + 1) * OUTD + t]
         + h4.z * ff1w[(e + 2) * OUTD + t] + h4.w * ff1w[(e + 3) * OUTD + t];
    }
    rowB[t] = fmaxf(r, 0.f);
  }
  __syncthreads();
  float tmp2;
  {
    float r = ff2b[t];
    const float4* cr = reinterpret_cast<const float4*>(rowB);
    for (int e4 = 0; e4 < 32; e4++) {
      float4 c4 = cr[e4];
      int e = e4 * 4;
      r += c4.x * ff2w[(e + 0) * OUTD + t] + c4.y * ff2w[(e + 1) * OUTD + t]
         + c4.z * ff2w[(e + 2) * OUTD + t] + c4.w * ff2w[(e + 3) * OUTD + t];
    }
    tmp2 = rowA[t] + r;
  }
  __syncthreads();
  {
    float v = tmp2;
#pragma unroll
    for (int k = 32; k >= 1; k >>= 1) v += __shfl_xor(v, k);
    if ((t & 63) == 0) lds2[t >> 6] = v;
    __syncthreads();
    float m = (lds2[0] + lds2[1]) * (1.0f / OUTD);
    __syncthreads();
    float u = tmp2 - m;
    float w = u * u;
#pragma unroll
    for (int k = 32; k >= 1; k >>= 1) w += __shfl_xor(w, k);
    if ((t & 63) == 0) lds2[t >> 6] = w;
    __syncthreads();
    float var = (lds2[0] + lds2[1]) * (1.0f / OUTD);
    rowA[t] = u * rsqrtf(var + 1e-5f) * ln2g[t] + ln2b[t];
  }
  __syncthreads();
  if (t < NCLS) {
    float acc = clfb[t];
    for (int d = 0; d < OUTD; d++) acc += rowA[d] * clfw[d * NCLS + t];
    out[bs * NCLS + t] = acc;
  }
}

extern "C" void kernel_launch(void* const* d_in, const int* in_sizes, int n_in,
                              void* d_out, int out_size, void* d_ws, size_t ws_size,
                              hipStream_t stream) {
  const float* x     = (const float*)d_in[0];
  const float* gum   = (const float*)d_in[1];
  const float* wq    = (const float*)d_in[2];
  const float* wk    = (const float*)d_in[3];
  const float* w1    = (const float*)d_in[4];
  const float* b1    = (const float*)d_in[5];
  const float* bn1g  = (const float*)d_in[6];
  const float* bn1b  = (const float*)d_in[7];
  const float* w2    = (const float*)d_in[8];
  const float* b2    = (const float*)d_in[9];
  const float* bn2g  = (const float*)d_in[10];
  const float* bn2b  = (const float*)d_in[11];
  const float* w3    = (const float*)d_in[12];
  const float* b3    = (const float*)d_in[13];
  const float* bn3g  = (const float*)d_in[14];
  const float* bn3b  = (const float*)d_in[15];
  const float* fcw   = (const float*)d_in[16];
  const float* fcb   = (const float*)d_in[17];
  const float* fc2w  = (const float*)d_in[18];
  const float* fc2b  = (const float*)d_in[19];
  const float* prot  = (const float*)d_in[20];
  const float* inw   = (const float*)d_in[21];
  const float* inb   = (const float*)d_in[22];
  const float* outw  = (const float*)d_in[23];
  const float* outb  = (const float*)d_in[24];
  const float* ln1g  = (const float*)d_in[25];
  const float* ln1b  = (const float*)d_in[26];
  const float* ln2g  = (const float*)d_in[27];
  const float* ln2b  = (const float*)d_in[28];
  const float* ff1w  = (const float*)d_in[29];
  const float* ff1b  = (const float*)d_in[30];
  const float* ff2w  = (const float*)d_in[31];
  const float* ff2b  = (const float*)d_in[32];
  const float* clfw  = (const float*)d_in[33];
  const float* clfb  = (const float*)d_in[34];
  float* out = (float*)d_out;

  int* sec_idx   = (int*)d_ws;
  int* proto_idx = sec_idx + NSAMPLE;
  short* w2hi = (short*)((float*)d_ws + WS_W2HI);
  short* w2lo = (short*)((float*)d_ws + WS_W2LO);
  short* w3hi = (short*)((float*)d_ws + WS_W3HI);
  short* w3lo = (short*)((float*)d_ws + WS_W3LO);
  float* P3   = (float*)d_ws + WS_P3;
  float* c3   = (float*)d_ws + WS_C3;
  float* wqT  = (float*)d_ws + WS_WQT;
  float* vbuf = (float*)d_ws + WS_V;
  float* ctxb = (float*)d_ws + WS_CTX;

  hipLaunchKernelGGL(prep_all_kernel, dim3(177), dim3(256), 0, stream,
                     w2, w3, w2hi, w2lo, w3hi, w3lo,
                     prot, fc2w, fcw, fcb, fc2b, P3, c3, wq, wqT);
  hipLaunchKernelGGL(attn_b_kernel, dim3(BS / MBX), dim3(512), 0, stream,
                     x, wk, wqT, vbuf);
  hipLaunchKernelGGL(attn_c_kernel, dim3(BS), dim3(192), 0, stream,
                     x, vbuf, gum, sec_idx);
  hipLaunchKernelGGL(conv_kernel, dim3(NSAMPLE), dim3(512), 0, stream,
                     x, sec_idx, w1, b1, bn1g, bn1b, w2hi, w2lo, b2, bn2g, bn2b,
                     w3hi, w3lo, b3, bn3g, bn3b, P3, c3, proto_idx);
  hipLaunchKernelGGL(seq_qk_attn_kernel, dim3(BB * NHEAD), dim3(256), 0, stream,
                     proto_idx, prot, inw, inb, ctxb);
  hipLaunchKernelGGL(seq_tail_kernel, dim3(BS), dim3(128), 0, stream,
                     proto_idx, prot, ctxb, outw, outb, ln1g, ln1b,
                     ff1w, ff1b, ff2w, ff2b, ln2g, ln2b, clfw, clfb, out);
}

// Round 17
// 171.327 us; speedup vs baseline: 1.1142x; 1.1142x over previous
//
#include <hip/hip_runtime.h>
#include <math.h>

#define BB 64
#define SS 21
#define NSAMP 3000
#define HID 500
#define SECN 6
#define NN 2
#define OUTD 128
#define NPROTO 25
#define NCLS 5
#define NHEAD 4
#define BS (BB*SS)          // 1344
#define NSAMPLE (BS*NN)     // 2688

#define C500 (-0.0184206807439523674f)   // -ln(1e4)/500
#define C128 (-0.07195578415606439f)     // -ln(1e4)/128
#define LSCALE 0.00745355992499929898f   // 1/(6*sqrt(500))

// ws float offsets
#define WS_W2HI 5376
#define WS_W2LO 8448
#define WS_W3HI 11520
#define WS_W3LO 23808
#define WS_P3   36096
#define WS_C3   55296
#define WS_WQT  55424
#define WS_PE1  183424                 // [6][500]   (gap: wqT ends at 183424, vbuf at 727424)
#define WS_PE2  186432                 // [21][128]
#define WS_V    727424
#define WS_CTX  (WS_V + 520192)

typedef __attribute__((ext_vector_type(8))) short short8;
typedef __attribute__((ext_vector_type(4))) short short4v;
typedef __attribute__((ext_vector_type(4))) float floatx4;

__device__ __forceinline__ short f2bf(float f) {
  unsigned u = __float_as_uint(f);
  u += 0x7FFF + ((u >> 16) & 1);          // RNE to bf16
  return (short)(u >> 16);
}
__device__ __forceinline__ float bf2f(short h) {
  return __uint_as_float(((unsigned)(unsigned short)h) << 16);
}

// ---------------- Kernel 0: weight splits + VQ prep + wq transpose + PE tables ----------------
__global__ __launch_bounds__(256) void prep_all_kernel(
    const float* __restrict__ w2, const float* __restrict__ w3,
    short* __restrict__ w2hi, short* __restrict__ w2lo,
    short* __restrict__ w3hi, short* __restrict__ w3lo,
    const float* __restrict__ protos, const float* __restrict__ fc2w,
    const float* __restrict__ fcw, const float* __restrict__ fcb,
    const float* __restrict__ fc2b,
    float* __restrict__ P3, float* __restrict__ c3,
    const float* __restrict__ wq, float* __restrict__ wqT,
    float* __restrict__ pe1, float* __restrict__ pe2) {
  __shared__ __align__(16) float p2row[256];
  __shared__ float red[256];
  __shared__ float tile[64][65];
  const int t = threadIdx.x;
  if (blockIdx.x < 120) {
    int idx = blockIdx.x * 256 + t;
    if (idx < 6144) {
      int ic = idx & 31, ck = idx >> 5, k = ck % 3, c = ck / 3;
      float v = w2[c * 96 + ic * 3 + k];
      int dst = (((k * 4 + (c >> 4)) * 64) + ((ic >> 3) * 16 + (c & 15))) * 8 + (ic & 7);
      short hi = f2bf(v);
      short lo = f2bf(v - bf2f(hi));
      w2hi[dst] = hi; w2lo[dst] = lo;
    } else if (idx < 30720) {
      int j = idx - 6144;
      int ic = j & 63, ck = j >> 6, k = ck % 3, c = ck / 3;
      float v = w3[(c * 64 + ic) * 3 + k];
      int s = k * 2 + (ic >> 5);
      int dst = (((s * 8 + (c >> 4)) * 64) + (((ic & 31) >> 3) * 16 + (c & 15))) * 8 + (ic & 7);
      short hi = f2bf(v);
      short lo = f2bf(v - bf2f(hi));
      w3hi[dst] = hi; w3lo[dst] = lo;
    }
    return;
  }
  if (blockIdx.x == 177) {               // pe1 [6][500] for attn_c
    for (int e = t; e < SECN * HID; e += 256) {
      int s = e / HID, h = e % HID;
      float div = expf((float)(2 * (h >> 1)) * C500);
      float ang = (float)s * div;
      pe1[e] = (h & 1) ? cosf(ang) : sinf(ang);
    }
    return;
  }
  if (blockIdx.x == 178) {               // pe2 [21][128] for seq kernels
    for (int e = t; e < SS * OUTD; e += 256) {
      int s = e >> 7, d = e & 127;
      float div = expf((float)(2 * (d >> 1)) * C128);
      float ang = (float)s * div;
      pe2[e] = (d & 1) ? cosf(ang) : sinf(ang);
    }
    return;
  }
  if (blockIdx.x >= 145) {               // wq transpose: 32 tile-blocks (145..176)
    int tid = blockIdx.x - 145;
    int h0 = (tid >> 2) * 64, c0 = (tid & 3) * 64;
    for (int e = t; e < 4096; e += 256) {
      int i = e >> 6, j = e & 63;
      if (h0 + i < 500) tile[j][i] = wq[(h0 + i) * 256 + c0 + j];
    }
    __syncthreads();
    for (int e = t; e < 4096; e += 256) {
      int c = e >> 6, hh = e & 63;
      if (h0 + hh < 500) wqT[(c0 + c) * 500 + h0 + hh] = tile[c][hh];
    }
    return;
  }
  const int p = blockIdx.x - 120, j = t;
  {
    const float4* pr = reinterpret_cast<const float4*>(protos + p * 128);
    const float4* wr = reinterpret_cast<const float4*>(fc2w + j * 128);
    float4 a4 = make_float4(0.f, 0.f, 0.f, 0.f);
    for (int c4 = 0; c4 < 32; c4++) {
      float4 a = pr[c4], b = wr[c4];
      a4.x += a.x * b.x; a4.y += a.y * b.y; a4.z += a.z * b.z; a4.w += a.w * b.w;
    }
    float v = (a4.x + a4.y) + (a4.z + a4.w);
    p2row[j] = v;
    float contrib = v * fcb[j];
    if (j < 128) {
      float pv = protos[p * 128 + j];
      contrib += pv * fc2b[j] - 0.5f * pv * pv;
    }
    red[j] = contrib;
  }
  __syncthreads();
  for (int s = 128; s > 0; s >>= 1) {
    if (j < s) red[j] += red[j + s];
    __syncthreads();
  }
  if (j == 0) c3[p] = red[0];
  for (int k = j; k < 768; k += 256) {
    const float4* fr = reinterpret_cast<const float4*>(fcw + k * 256);
    const float4* p2 = reinterpret_cast<const float4*>(p2row);
    float4 a4 = make_float4(0.f, 0.f, 0.f, 0.f);
    for (int j4 = 0; j4 < 64; j4++) {
      float4 a = p2[j4], b = fr[j4];
      a4.x += a.x * b.x; a4.y += a.y * b.y; a4.z += a.z * b.z; a4.w += a.w * b.w;
    }
    P3[p * 768 + k] = (a4.x + a4.y) + (a4.z + a4.w);
  }
}

// ---------------- Kernel 1b: fused xsum -> ks -> v (4 samples/block, 336 blocks, K-split) ----------------
#define MBX 4
__global__ __launch_bounds__(512) void attn_b_kernel(
    const float* __restrict__ x, const float* __restrict__ wk,
    const float* __restrict__ wqT, float* __restrict__ v) {
  __shared__ __align__(16) float pesum[500];
  __shared__ __align__(16) float xs[MBX * 500];
  __shared__ __align__(16) float ksp[2 * 256 * MBX];
  __shared__ __align__(16) float ks_t[256 * MBX];
  const int blk = blockIdx.x, t = threadIdx.x;

  if (t < 125) {
    float div0 = expf((float)(4 * t) * C500);
    float div1 = expf((float)(4 * t + 2) * C500);
    float s0 = 0.f, c0 = 0.f, s1 = 0.f, c1 = 0.f;
#pragma unroll
    for (int s = 0; s < SECN; s++) {
      float a0 = (float)s * div0, a1 = (float)s * div1;
      s0 += sinf(a0); c0 += cosf(a0);
      s1 += sinf(a1); c1 += cosf(a1);
    }
    reinterpret_cast<float4*>(pesum)[t] = make_float4(s0, c0, s1, c1);
  }
  __syncthreads();

  for (int e = t; e < MBX * 125; e += 512) {
    int m = e / 125, h4 = e % 125;
    const float4* xr = reinterpret_cast<const float4*>(x) + (blk * MBX + m) * 750;
    float4 a = xr[h4];
#pragma unroll
    for (int s = 1; s < SECN; s++) {
      float4 b = xr[s * 125 + h4];
      a.x += b.x; a.y += b.y; a.z += b.z; a.w += b.w;
    }
    float4 pe = reinterpret_cast<float4*>(pesum)[h4];
    a.x += pe.x; a.y += pe.y; a.z += pe.z; a.w += pe.w;
    reinterpret_cast<float4*>(xs)[m * 125 + h4] = a;
  }
  __syncthreads();

  {
    int c = t & 255, kh = t >> 8;
    float acc[MBX];
#pragma unroll
    for (int m = 0; m < MBX; m++) acc[m] = 0.f;
    int b4 = kh ? 63 : 0, e4 = kh ? 125 : 63;
    const float4* xsb = reinterpret_cast<const float4*>(xs);
    for (int i4 = b4; i4 < e4; i4++) {
      int i = i4 * 4;
      float w0 = wk[(i + 0) * 256 + c];
      float w1 = wk[(i + 1) * 256 + c];
      float w2v = wk[(i + 2) * 256 + c];
      float w3v = wk[(i + 3) * 256 + c];
#pragma unroll
      for (int m = 0; m < MBX; m++) {
        float4 xv = xsb[m * 125 + i4];
        acc[m] += xv.x * w0 + xv.y * w1 + xv.z * w2v + xv.w * w3v;
      }
    }
#pragma unroll
    for (int m = 0; m < MBX; m++)
      ksp[(kh * 256 + c) * MBX + m] = acc[m];
  }
  __syncthreads();
  for (int e = t; e < 256 * MBX; e += 512) ks_t[e] = ksp[e] + ksp[256 * MBX + e];
  __syncthreads();

  if (t < 500) {
    int h = t;
#pragma unroll
    for (int n = 0; n < 2; n++) {
      float acc[MBX];
#pragma unroll
      for (int m = 0; m < MBX; m++) acc[m] = 0.f;
      const float* wcol = wqT + (n * 128) * 500 + h;
      const floatx4* ktb = (const floatx4*)ks_t + n * 128;
      for (int c = 0; c < 128; c++) {
        float w = wcol[c * 500];
        floatx4 k0 = ktb[c];
        acc[0] += w * k0[0]; acc[1] += w * k0[1]; acc[2] += w * k0[2]; acc[3] += w * k0[3];
      }
#pragma unroll
      for (int m = 0; m < MBX; m++)
        v[((blk * MBX + m) * 2 + n) * 500 + h] = acc[m];
    }
  }
}

// ---------------- Kernel 1c: logits = (x+pe).v + gumbel -> argmax (PE from table) ----------------
__global__ __launch_bounds__(192) void attn_c_kernel(
    const float* __restrict__ x, const float* __restrict__ v,
    const float* __restrict__ pe1,
    const float* __restrict__ gumbel, int* __restrict__ sec_idx) {
  __shared__ float lgsh[NN][SECN];
  const int bs = blockIdx.x, t = threadIdx.x;
  const int s = t >> 5, lane = t & 31;
  const float4* x4 = reinterpret_cast<const float4*>(x) + bs * 750 + s * 125;
  const float4* pe4 = reinterpret_cast<const float4*>(pe1) + s * 125;
  const float4* v0 = reinterpret_cast<const float4*>(v) + bs * 250;
  const float4* v1 = v0 + 125;
  float a0 = 0.f, a1 = 0.f;
  for (int h4 = lane; h4 < 125; h4 += 32) {
    float4 xv = x4[h4];
    float4 pv = pe4[h4];
    xv.x += pv.x; xv.y += pv.y; xv.z += pv.z; xv.w += pv.w;
    float4 w0 = v0[h4], w1 = v1[h4];
    a0 += xv.x * w0.x + xv.y * w0.y + xv.z * w0.z + xv.w * w0.w;
    a1 += xv.x * w1.x + xv.y * w1.y + xv.z * w1.z + xv.w * w1.w;
  }
#pragma unroll
  for (int m = 16; m >= 1; m >>= 1) {
    a0 += __shfl_xor(a0, m);
    a1 += __shfl_xor(a1, m);
  }
  if (lane == 0) {
    lgsh[0][s] = a0 * LSCALE + gumbel[(bs * 2 + 0) * SECN + s];
    lgsh[1][s] = a1 * LSCALE + gumbel[(bs * 2 + 1) * SECN + s];
  }
  __syncthreads();
  if (t < 2) {
    int best = 0; float bv = lgsh[t][0];
    for (int i = 1; i < SECN; i++) {
      float q = lgsh[t][i];
      if (q > bv) { bv = q; best = i; }
    }
    sec_idx[bs * 2 + t] = best;
  }
}

// ---------------- Kernel 2: conv encoder (R14 exact: in0p staged, half-split conv2) + VQ ----------------
#define CONV_LDS 46944
#define ST2P 68
__global__ __launch_bounds__(512, 6) void conv_kernel(
    const float* __restrict__ x, const int* __restrict__ sec_idx,
    const float* __restrict__ w1, const float* __restrict__ b1,
    const float* __restrict__ bn1g, const float* __restrict__ bn1b,
    const short* __restrict__ w2hi, const short* __restrict__ w2lo,
    const float* __restrict__ b2,
    const float* __restrict__ bn2g, const float* __restrict__ bn2b,
    const short* __restrict__ w3hi, const short* __restrict__ w3lo,
    const float* __restrict__ b3,
    const float* __restrict__ bn3g, const float* __restrict__ bn3b,
    const float* __restrict__ P3, const float* __restrict__ c3,
    int* __restrict__ proto_idx) {
  __shared__ __align__(16) char smem[CONV_LDS];
  short* act1_hi  = (short*)smem;               // [130][40]
  short* act1_lo  = (short*)(smem + 10400);
  short* act2p_hi = (short*)(smem + 20800);     // [34][68]
  short* act2p_lo = (short*)(smem + 25424);
  float* featsh   = (float*)smem;               // [768] (alias act1, after 3b)
  float* sc25     = (float*)(smem + 3072);      // [25]
  float* in0p  = (float*)(smem + 30048);        // [512]
  float* act2t = (float*)(smem + 30048);        // [64][64] swizzled (half)
  float* act3t = (float*)(smem + 30048);        // [32][132]
  float* bnd   = (float*)(smem + 46432);        // [64] boundary partial

  const int sample = blockIdx.x;
  const int t = threadIdx.x;
  const int bsIdx = sample >> 1;
  const float bnscale = rsqrtf(1.0f + 1e-5f);
  const int wv = t >> 6, l = t & 63, lr = l & 15, lg2 = l >> 4;

  // ---- phase 1: load x section; zero act1 + act2p pad rows ----
  {
    int sec = sec_idx[sample];
    const float* src = &x[bsIdx * NSAMP + sec * HID];
    if (t < 512) in0p[t] = (t >= 1 && t <= 500) ? src[t - 1] : 0.f;
    if (t < 200) {
      int r = t / 40; r = (r == 0) ? 0 : 125 + r;
      int idx = r * 40 + t % 40;
      act1_hi[idx] = 0; act1_lo[idx] = 0;
    }
    if (t >= 256 && t < 256 + 153) {
      int tt = t - 256;
      for (int i = tt; i < 612; i += 153) {     // act2p rows 0, 26..33
        int r = i / ST2P; r = (r == 0) ? 0 : 25 + r;
        int idx = r * ST2P + i % ST2P;
        act2p_hi[idx] = 0; act2p_lo[idx] = 0;
      }
    }
  }
  __syncthreads();

  // ---- phase 2: conv1 + relu + pool4 + bn -> act1 ----
  {
    int ic = t & 31;
    float w0 = w1[ic * 3], w1v = w1[ic * 3 + 1], w2v = w1[ic * 3 + 2];
    float bb = b1[ic];
    float g = bn1g[ic] * bnscale, be = bn1b[ic];
    for (int p = t >> 5; p < 125; p += 16) {
      int base = 4 * p;
      float xm1 = in0p[base], x0 = in0p[base + 1], x1 = in0p[base + 2],
            x2 = in0p[base + 3], x3 = in0p[base + 4], x4 = in0p[base + 5];
      float a0 = bb + w0 * xm1 + w1v * x0 + w2v * x1;
      float a1 = bb + w0 * x0  + w1v * x1 + w2v * x2;
      float a2 = bb + w0 * x1  + w1v * x2 + w2v * x3;
      float a3 = bb + w0 * x2  + w1v * x3 + w2v * x4;
      float m = fmaxf(fmaxf(fmaxf(fmaxf(a0, a1), a2), a3), 0.f);
      float v = m * g + be;
      short hi = f2bf(v);
      short lo = f2bf(v - bf2f(hi));
      act1_hi[(p + 1) * 40 + ic] = hi;
      act1_lo[(p + 1) * 40 + ic] = lo;
    }
  }
  __syncthreads();

#define A2T(r, c) act2t[(r) * 64 + ((((c) >> 2) ^ ((r) & 15)) << 2) + ((c) & 3)]
  // ---- phases 3a/4a, 3b/4b: conv2 MFMA + pool5 over two position halves ----
#pragma unroll
  for (int h = 0; h < 2; h++) {
    {
      int tl = wv & 3, mh = wv >> 2;
      int lrow = tl * 16 + lr;
      floatx4 acc[2];
      acc[0] = (floatx4){0.f, 0.f, 0.f, 0.f};
      acc[1] = acc[0];
#pragma unroll
      for (int s = 0; s < 3; s++) {
        short8 Ah[2], Al[2], Bh, Bl;
#pragma unroll
        for (int j = 0; j < 2; j++) {
          int m = mh * 2 + j;
          int aoff = ((s * 4 + m) * 64 + l) * 8;
          Ah[j] = *(const short8*)(w2hi + aoff);
          Al[j] = *(const short8*)(w2lo + aoff);
        }
        {
          int boff = (h * 64 + lrow + s) * 40 + lg2 * 8;
          Bh = *(const short8*)(act1_hi + boff);
          Bl = *(const short8*)(act1_lo + boff);
        }
#pragma unroll
        for (int j = 0; j < 2; j++) {
          acc[j] = __builtin_amdgcn_mfma_f32_16x16x32_bf16(Ah[j], Bh, acc[j], 0, 0, 0);
          acc[j] = __builtin_amdgcn_mfma_f32_16x16x32_bf16(Ah[j], Bl, acc[j], 0, 0, 0);
          acc[j] = __builtin_amdgcn_mfma_f32_16x16x32_bf16(Al[j], Bh, acc[j], 0, 0, 0);
        }
      }
#pragma unroll
      for (int j = 0; j < 2; j++) {
        int m = mh * 2 + j;
        int swz = (m * 4 + lg2) ^ lr;
        *(floatx4*)(act2t + lrow * 64 + swz * 4) = acc[j];
      }
    }
    __syncthreads();
    {
      int ic = t & 63;
      float bb = b2[ic], g = bn2g[ic] * bnscale, be = bn2b[ic];
      if (h == 0) {
        for (int pw = t >> 6; pw < 13; pw += 8) {
          if (pw < 12) {
            int base = 5 * pw;
            float m = A2T(base, ic);
            m = fmaxf(m, A2T(base + 1, ic));
            m = fmaxf(m, A2T(base + 2, ic));
            m = fmaxf(m, A2T(base + 3, ic));
            m = fmaxf(m, A2T(base + 4, ic));
            float v = fmaxf(m + bb, 0.f) * g + be;
            short hi = f2bf(v);
            short lo = f2bf(v - bf2f(hi));
            act2p_hi[(pw + 1) * ST2P + ic] = hi;
            act2p_lo[(pw + 1) * ST2P + ic] = lo;
          } else {
            float m = A2T(60, ic);
            m = fmaxf(m, A2T(61, ic));
            m = fmaxf(m, A2T(62, ic));
            m = fmaxf(m, A2T(63, ic));
            bnd[ic] = m;
          }
        }
      } else {
        for (int pw = 12 + (t >> 6); pw < 25; pw += 8) {
          float m;
          if (pw == 12) {
            m = fmaxf(bnd[ic], A2T(0, ic));
          } else {
            int base = 5 * pw - 64;
            m = A2T(base, ic);
            m = fmaxf(m, A2T(base + 1, ic));
            m = fmaxf(m, A2T(base + 2, ic));
            m = fmaxf(m, A2T(base + 3, ic));
            m = fmaxf(m, A2T(base + 4, ic));
          }
          float v = fmaxf(m + bb, 0.f) * g + be;
          short hi = f2bf(v);
          short lo = f2bf(v - bf2f(hi));
          act2p_hi[(pw + 1) * ST2P + ic] = hi;
          act2p_lo[(pw + 1) * ST2P + ic] = lo;
        }
      }
    }
    __syncthreads();
  }
#undef A2T

  // ---- phase 5: conv3 MFMA — wave wv owns ch-group wv; B via 2x b64 ----
  {
    floatx4 acc[2];
#pragma unroll
    for (int nn = 0; nn < 2; nn++) acc[nn] = (floatx4){0.f, 0.f, 0.f, 0.f};
#pragma unroll
    for (int s = 0; s < 6; s++) {
      short8 Ah, Al, Bh[2], Bl[2];
      {
        int aoff = ((s * 8 + wv) * 64 + l) * 8;
        Ah = *(const short8*)(w3hi + aoff);
        Al = *(const short8*)(w3lo + aoff);
      }
#pragma unroll
      for (int nn = 0; nn < 2; nn++) {
        int boff = (nn * 16 + lr + (s >> 1)) * ST2P + (s & 1) * 32 + lg2 * 8;
        short4v h0 = *(const short4v*)(act2p_hi + boff);
        short4v h1 = *(const short4v*)(act2p_hi + boff + 4);
        short4v l0 = *(const short4v*)(act2p_lo + boff);
        short4v l1 = *(const short4v*)(act2p_lo + boff + 4);
        Bh[nn] = (short8){h0[0], h0[1], h0[2], h0[3], h1[0], h1[1], h1[2], h1[3]};
        Bl[nn] = (short8){l0[0], l0[1], l0[2], l0[3], l1[0], l1[1], l1[2], l1[3]};
      }
#pragma unroll
      for (int nn = 0; nn < 2; nn++) {
        acc[nn] = __builtin_amdgcn_mfma_f32_16x16x32_bf16(Ah, Bh[nn], acc[nn], 0, 0, 0);
        acc[nn] = __builtin_amdgcn_mfma_f32_16x16x32_bf16(Ah, Bl[nn], acc[nn], 0, 0, 0);
        acc[nn] = __builtin_amdgcn_mfma_f32_16x16x32_bf16(Al, Bh[nn], acc[nn], 0, 0, 0);
      }
    }
#pragma unroll
    for (int nn = 0; nn < 2; nn++) {
      int p = nn * 16 + lr;
      *(floatx4*)(act3t + p * 132 + wv * 16 + lg2 * 4) = acc[nn];
    }
  }
  __syncthreads();

  // ---- phase 6: pool4 + bias + relu + bn -> featsh ----
  {
    int c = t & 127;
    float bb = b3[c], g = bn3g[c] * bnscale, be = bn3b[c];
    for (int pw = t >> 7; pw < 6; pw += 4) {
      int base = 4 * pw;
      float m = act3t[base * 132 + c];
      m = fmaxf(m, act3t[(base + 1) * 132 + c]);
      m = fmaxf(m, act3t[(base + 2) * 132 + c]);
      m = fmaxf(m, act3t[(base + 3) * 132 + c]);
      float v = fmaxf(m + bb, 0.f) * g + be;
      featsh[c * 6 + pw] = v;
    }
  }
  __syncthreads();

  // ---- phase 7: folded VQ scores + argmax ----
  if (t < NPROTO * 8) {
    int p = t >> 3, part = t & 7;
    const float4* pr = reinterpret_cast<const float4*>(P3 + p * 768 + part * 96);
    const float4* fr = reinterpret_cast<const float4*>(featsh + part * 96);
    float4 a4 = make_float4(0.f, 0.f, 0.f, 0.f);
#pragma unroll
    for (int i = 0; i < 24; i++) {
      float4 w = pr[i], f = fr[i];
      a4.x += w.x * f.x; a4.y += w.y * f.y; a4.z += w.z * f.z; a4.w += w.w * f.w;
    }
    float a = (a4.x + a4.y) + (a4.z + a4.w);
    a += __shfl_xor(a, 1);
    a += __shfl_xor(a, 2);
    a += __shfl_xor(a, 4);
    if (part == 0) sc25[p] = a + c3[p];
  }
  __syncthreads();
  if (t == 0) {
    int best = 0; float bv = sc25[0];
    for (int i = 1; i < NPROTO; i++) {
      float v = sc25[i];
      if (v > bv) { bv = v; best = i; }
    }
    proto_idx[sample] = best;
  }
}

// ---------------- Kernel 3ab: fused qkv + attention per (b, head) (PE from table) ----------------
__global__ __launch_bounds__(256) void seq_qk_attn_kernel(
    const int* __restrict__ proto_idx, const float* __restrict__ protos,
    const float* __restrict__ pe2,
    const float* __restrict__ inw, const float* __restrict__ inb,
    float* __restrict__ ctxbuf) {
  __shared__ __align__(16) float hsh[SS * OUTD];
  __shared__ float qs_[SS][32], ks_[SS][32], vs_[SS][32];
  __shared__ float sc_[SS][SS + 1];
  const int b = blockIdx.x >> 2, hd = blockIdx.x & 3;
  const int t = threadIdx.x;

  for (int o = t; o < SS * OUTD; o += 256) {
    int s = o >> 7, d = o & 127;
    int i0 = proto_idx[(b * SS + s) * 2];
    int i1 = proto_idx[(b * SS + s) * 2 + 1];
    float pc = 0.5f * (protos[i0 * OUTD + d] + protos[i1 * OUTD + d]);
    hsh[o] = pc + pe2[o];
  }
  __syncthreads();

  for (int o = t; o < SS * 96; o += 256) {
    int s = o / 96, j = o % 96;
    int sec = j >> 5, dd = j & 31;
    int col = sec * 128 + hd * 32 + dd;
    float a = inb[col];
    const float4* hr = reinterpret_cast<const float4*>(&hsh[s * OUTD]);
    for (int d4 = 0; d4 < 32; d4++) {
      float4 h4 = hr[d4];
      int d = d4 * 4;
      a += h4.x * inw[(d + 0) * 384 + col] + h4.y * inw[(d + 1) * 384 + col]
         + h4.z * inw[(d + 2) * 384 + col] + h4.w * inw[(d + 3) * 384 + col];
    }
    if (sec == 0) qs_[s][dd] = a;
    else if (sec == 1) ks_[s][dd] = a;
    else vs_[s][dd] = a;
  }
  __syncthreads();

  for (int e = t; e < SS * SS; e += 256) {
    int qs = e / SS, ks = e % SS;
    float a = 0.f;
#pragma unroll
    for (int d = 0; d < 32; d++) a += qs_[qs][d] * ks_[ks][d];
    sc_[qs][ks] = a * 0.17677669529663689f;
  }
  __syncthreads();
  if (t < SS) {
    float mx = sc_[t][0];
    for (int i = 1; i < SS; i++) mx = fmaxf(mx, sc_[t][i]);
    float sum = 0.f;
    for (int i = 0; i < SS; i++) { float e = expf(sc_[t][i] - mx); sc_[t][i] = e; sum += e; }
    float inv = 1.f / sum;
    for (int i = 0; i < SS; i++) sc_[t][i] *= inv;
  }
  __syncthreads();
  for (int e = t; e < SS * 32; e += 256) {
    int qs = e >> 5, dd = e & 31;
    float a = 0.f;
#pragma unroll
    for (int ks = 0; ks < SS; ks++) a += sc_[qs][ks] * vs_[ks][dd];
    ctxbuf[(b * SS + qs) * OUTD + hd * 32 + dd] = a;
  }
}

// ---------------- Kernel 3c: out proj + LN1 + FF + LN2 + classifier (PE from table) ----------------
__global__ __launch_bounds__(128) void seq_tail_kernel(
    const int* __restrict__ proto_idx, const float* __restrict__ protos,
    const float* __restrict__ pe2,
    const float* __restrict__ ctxbuf,
    const float* __restrict__ outw, const float* __restrict__ outb,
    const float* __restrict__ ln1g, const float* __restrict__ ln1b,
    const float* __restrict__ ff1w, const float* __restrict__ ff1b,
    const float* __restrict__ ff2w, const float* __restrict__ ff2b,
    const float* __restrict__ ln2g, const float* __restrict__ ln2b,
    const float* __restrict__ clfw, const float* __restrict__ clfb,
    float* __restrict__ out) {
  __shared__ __align__(16) float rowA[OUTD];
  __shared__ __align__(16) float rowB[OUTD];
  __shared__ float lds2[2];
  const int bs = blockIdx.x, t = threadIdx.x;
  const int s = bs % SS;

  rowA[t] = ctxbuf[bs * OUTD + t];
  __syncthreads();
  float a = outb[t];
  {
    const float4* cr = reinterpret_cast<const float4*>(rowA);
    for (int e4 = 0; e4 < 32; e4++) {
      float4 c4 = cr[e4];
      int e = e4 * 4;
      a += c4.x * outw[(e + 0) * OUTD + t] + c4.y * outw[(e + 1) * OUTD + t]
         + c4.z * outw[(e + 2) * OUTD + t] + c4.w * outw[(e + 3) * OUTD + t];
    }
  }
  float hv;
  {
    int i0 = proto_idx[bs * 2], i1 = proto_idx[bs * 2 + 1];
    float pc = 0.5f * (protos[i0 * OUTD + t] + protos[i1 * OUTD + t]);
    hv = pc + pe2[s * OUTD + t];
  }
  float tmp = hv + a;
  {
    float v = tmp;
#pragma unroll
    for (int k = 32; k >= 1; k >>= 1) v += __shfl_xor(v, k);
    if ((t & 63) == 0) lds2[t >> 6] = v;
    __syncthreads();
    float m = (lds2[0] + lds2[1]) * (1.0f / OUTD);
    __syncthreads();
    float u = tmp - m;
    float w = u * u;
#pragma unroll
    for (int k = 32; k >= 1; k >>= 1) w += __shfl_xor(w, k);
    if ((t & 63) == 0) lds2[t >> 6] = w;
    __syncthreads();
    float var = (lds2[0] + lds2[1]) * (1.0f / OUTD);
    __syncthreads();
    rowA[t] = u * rsqrtf(var + 1e-5f) * ln1g[t] + ln1b[t];
  }
  __syncthreads();
  {
    float r = ff1b[t];
    const float4* hr = reinterpret_cast<const float4*>(rowA);
    for (int e4 = 0; e4 < 32; e4++) {
      float4 h4 = hr[e4];
      int e = e4 * 4;
      r += h4.x * ff1w[(e + 0) * OUTD + t] + h4.y * ff1w[(e + 1) * OUTD + t]
         + h4.z * ff1w[(e + 2) * OUTD + t] + h4.w * ff1w[(e + 3) * OUTD + t];
    }
    rowB[t] = fmaxf(r, 0.f);
  }
  __syncthreads();
  float tmp2;
  {
    float r = ff2b[t];
    const float4* cr = reinterpret_cast<const float4*>(rowB);
    for (int e4 = 0; e4 < 32; e4++) {
      float4 c4 = cr[e4];
      int e = e4 * 4;
      r += c4.x * ff2w[(e + 0) * OUTD + t] + c4.y * ff2w[(e + 1) * OUTD + t]
         + c4.z * ff2w[(e + 2) * OUTD + t] + c4.w * ff2w[(e + 3) * OUTD + t];
    }
    tmp2 = rowA[t] + r;
  }
  __syncthreads();
  {
    float v = tmp2;
#pragma unroll
    for (int k = 32; k >= 1; k >>= 1) v += __shfl_xor(v, k);
    if ((t & 63) == 0) lds2[t >> 6] = v;
    __syncthreads();
    float m = (lds2[0] + lds2[1]) * (1.0f / OUTD);
    __syncthreads();
    float u = tmp2 - m;
    float w = u * u;
#pragma unroll
    for (int k = 32; k >= 1; k >>= 1) w += __shfl_xor(w, k);
    if ((t & 63) == 0) lds2[t >> 6] = w;
    __syncthreads();
    float var = (lds2[0] + lds2[1]) * (1.0f / OUTD);
    rowA[t] = u * rsqrtf(var + 1e-5f) * ln2g[t] + ln2b[t];
  }
  __syncthreads();
  if (t < NCLS) {
    float acc = clfb[t];
    for (int d = 0; d < OUTD; d++) acc += rowA[d] * clfw[d * NCLS + t];
    out[bs * NCLS + t] = acc;
  }
}

extern "C" void kernel_launch(void* const* d_in, const int* in_sizes, int n_in,
                              void* d_out, int out_size, void* d_ws, size_t ws_size,
                              hipStream_t stream) {
  const float* x     = (const float*)d_in[0];
  const float* gum   = (const float*)d_in[1];
  const float* wq    = (const float*)d_in[2];
  const float* wk    = (const float*)d_in[3];
  const float* w1    = (const float*)d_in[4];
  const float* b1    = (const float*)d_in[5];
  const float* bn1g  = (const float*)d_in[6];
  const float* bn1b  = (const float*)d_in[7];
  const float* w2    = (const float*)d_in[8];
  const float* b2    = (const float*)d_in[9];
  const float* bn2g  = (const float*)d_in[10];
  const float* bn2b  = (const float*)d_in[11];
  const float* w3    = (const float*)d_in[12];
  const float* b3    = (const float*)d_in[13];
  const float* bn3g  = (const float*)d_in[14];
  const float* bn3b  = (const float*)d_in[15];
  const float* fcw   = (const float*)d_in[16];
  const float* fcb   = (const float*)d_in[17];
  const float* fc2w  = (const float*)d_in[18];
  const float* fc2b  = (const float*)d_in[19];
  const float* prot  = (const float*)d_in[20];
  const float* inw   = (const float*)d_in[21];
  const float* inb   = (const float*)d_in[22];
  const float* outw  = (const float*)d_in[23];
  const float* outb  = (const float*)d_in[24];
  const float* ln1g  = (const float*)d_in[25];
  const float* ln1b  = (const float*)d_in[26];
  const float* ln2g  = (const float*)d_in[27];
  const float* ln2b  = (const float*)d_in[28];
  const float* ff1w  = (const float*)d_in[29];
  const float* ff1b  = (const float*)d_in[30];
  const float* ff2w  = (const float*)d_in[31];
  const float* ff2b  = (const float*)d_in[32];
  const float* clfw  = (const float*)d_in[33];
  const float* clfb  = (const float*)d_in[34];
  float* out = (float*)d_out;

  int* sec_idx   = (int*)d_ws;
  int* proto_idx = sec_idx + NSAMPLE;
  short* w2hi = (short*)((float*)d_ws + WS_W2HI);
  short* w2lo = (short*)((float*)d_ws + WS_W2LO);
  short* w3hi = (short*)((float*)d_ws + WS_W3HI);
  short* w3lo = (short*)((float*)d_ws + WS_W3LO);
  float* P3   = (float*)d_ws + WS_P3;
  float* c3   = (float*)d_ws + WS_C3;
  float* wqT  = (float*)d_ws + WS_WQT;
  float* pe1  = (float*)d_ws + WS_PE1;
  float* pe2  = (float*)d_ws + WS_PE2;
  float* vbuf = (float*)d_ws + WS_V;
  float* ctxb = (float*)d_ws + WS_CTX;

  hipLaunchKernelGGL(prep_all_kernel, dim3(179), dim3(256), 0, stream,
                     w2, w3, w2hi, w2lo, w3hi, w3lo,
                     prot, fc2w, fcw, fcb, fc2b, P3, c3, wq, wqT, pe1, pe2);
  hipLaunchKernelGGL(attn_b_kernel, dim3(BS / MBX), dim3(512), 0, stream,
                     x, wk, wqT, vbuf);
  hipLaunchKernelGGL(attn_c_kernel, dim3(BS), dim3(192), 0, stream,
                     x, vbuf, pe1, gum, sec_idx);
  hipLaunchKernelGGL(conv_kernel, dim3(NSAMPLE), dim3(512), 0, stream,
                     x, sec_idx, w1, b1, bn1g, bn1b, w2hi, w2lo, b2, bn2g, bn2b,
                     w3hi, w3lo, b3, bn3g, bn3b, P3, c3, proto_idx);
  hipLaunchKernelGGL(seq_qk_attn_kernel, dim3(BB * NHEAD), dim3(256), 0, stream,
                     proto_idx, prot, pe2, inw, inb, ctxb);
  hipLaunchKernelGGL(seq_tail_kernel, dim3(BS), dim3(128), 0, stream,
                     proto_idx, prot, pe2, ctxb, outw, outb, ln1g, ln1b,
                     ff1w, ff1b, ff2w, ff2b, ln2g, ln2b, clfw, clfb, out);
}